// Round 1
// baseline (525.312 us; speedup 1.0000x reference)
//
#include <hip/hip_runtime.h>

// LRN: out = x / (2 + 1e-4 * ssq)^0.75, ssq = 5x5 spatial box sum of x^2 (zero pad 2).
// x: (16, 96, 224, 224) fp32. Memory-bound: target ~616 MB HBM traffic.
//
// Layout: each lane owns a float4 column group (4 consecutive w) of one (n,c)
// plane and slides down rows, keeping 5 horizontal row-sums in registers.
// 224 cols = 56 float4 lanes (56 of 64 active per wave). 8 row-strips of 28
// rows per plane. Block (64,4) = 4 strip-jobs; grid = 16*96*8/4 = 3072.

#define LRN_H 224
#define LRN_W 224
#define LRN_WQ 56          // float4 groups per row
#define LRN_STRIPS 8
#define LRN_ROWS 28        // rows per strip
#define LRN_PLANE (LRN_H * LRN_W)

__device__ __forceinline__ float4 lrn_zero4() { return make_float4(0.f, 0.f, 0.f, 0.f); }

__device__ __forceinline__ float4 lrn_rowsum(const float* __restrict__ px, int row, int col, int q) {
    // 5-tap horizontal sum of squares for 4 outputs at columns col..col+3.
    if (row < 0 || row >= LRN_H) return lrn_zero4();
    const float* rp = px + row * LRN_W + col;
    float4 xc = *(const float4*)rp;
    float4 xl = (q > 0)          ? *(const float4*)(rp - 4) : lrn_zero4();
    float4 xr = (q < LRN_WQ - 1) ? *(const float4*)(rp + 4) : lrn_zero4();
    float a  = xl.z * xl.z;
    float b  = xl.w * xl.w;
    float c0 = xc.x * xc.x;
    float c1 = xc.y * xc.y;
    float c2 = xc.z * xc.z;
    float c3 = xc.w * xc.w;
    float d0 = xr.x * xr.x;
    float d1 = xr.y * xr.y;
    float t = c1 + c2;           // shared by all four windows
    float4 r;
    r.x = a + b + c0 + t;        // cols col-2..col+2
    r.y = b + c0 + t + c3;       // cols col-1..col+3
    r.z = c0 + t + c3 + d0;      // cols col..col+4
    r.w = t + c3 + d0 + d1;      // cols col+1..col+5
    return r;
}

__global__ __launch_bounds__(256) void LocalResponseNorm_17420387352942_kernel(
        const float* __restrict__ x, float* __restrict__ out) {
    const int q = threadIdx.x;           // float4 column group
    if (q >= LRN_WQ) return;             // lanes 56..63 idle
    const int job = blockIdx.x * 4 + threadIdx.y;   // plane*8 + strip
    const int plane = job >> 3;
    const int strip = job & 7;
    const float* px = x + (size_t)plane * LRN_PLANE;
    float* po = out + (size_t)plane * LRN_PLANE;
    const int s0 = strip * LRN_ROWS;
    const int col = q << 2;

    // Prime circular buffer: r0..r3 = rowsums of rows s0-2 .. s0+1
    float4 r0 = lrn_rowsum(px, s0 - 2, col, q);
    float4 r1 = lrn_rowsum(px, s0 - 1, col, q);
    float4 r2 = lrn_rowsum(px, s0,     col, q);
    float4 r3 = lrn_rowsum(px, s0 + 1, col, q);

#pragma unroll
    for (int h = s0; h < s0 + LRN_ROWS; ++h) {
        float4 r4 = lrn_rowsum(px, h + 2, col, q);
        float4 s;
        s.x = r0.x + r1.x + r2.x + r3.x + r4.x;
        s.y = r0.y + r1.y + r2.y + r3.y + r4.y;
        s.z = r0.z + r1.z + r2.z + r3.z + r4.z;
        s.w = r0.w + r1.w + r2.w + r3.w + r4.w;

        float4 xv = *(const float4*)(px + h * LRN_W + col);   // L1/L2 hot (loaded 2 iters ago)
        float4 o;
        {
            float d = fmaf(1e-4f, s.x, 2.0f);
            float r = __builtin_amdgcn_rsqf(d);               // d^-0.5
            o.x = xv.x * r * __builtin_amdgcn_sqrtf(r);       // * d^-0.25
        }
        {
            float d = fmaf(1e-4f, s.y, 2.0f);
            float r = __builtin_amdgcn_rsqf(d);
            o.y = xv.y * r * __builtin_amdgcn_sqrtf(r);
        }
        {
            float d = fmaf(1e-4f, s.z, 2.0f);
            float r = __builtin_amdgcn_rsqf(d);
            o.z = xv.z * r * __builtin_amdgcn_sqrtf(r);
        }
        {
            float d = fmaf(1e-4f, s.w, 2.0f);
            float r = __builtin_amdgcn_rsqf(d);
            o.w = xv.w * r * __builtin_amdgcn_sqrtf(r);
        }
        *(float4*)(po + h * LRN_W + col) = o;

        r0 = r1; r1 = r2; r2 = r3; r3 = r4;
    }
}

extern "C" void kernel_launch(void* const* d_in, const int* in_sizes, int n_in,
                              void* d_out, int out_size, void* d_ws, size_t ws_size,
                              hipStream_t stream) {
    const float* x = (const float*)d_in[0];
    float* out = (float*)d_out;
    // jobs = 16*96 planes * 8 strips = 12288; 4 jobs per block
    dim3 block(64, 4, 1);
    dim3 grid(12288 / 4, 1, 1);
    LocalResponseNorm_17420387352942_kernel<<<grid, block, 0, stream>>>(x, out);
}